// Round 1
// 2501.366 us; speedup vs baseline: 1.1714x; 1.1714x over previous
//
#include <hip/hip_runtime.h>
#include <hip/hip_bf16.h>

#define N_NODES 100000
#define N_EDGES 1600000
#define DIM 128
#define NLAY 3
#define NRES 3
#define NCODE 16
#define NGRAPH 512

using bf16 = __hip_bfloat16;

__device__ inline void atomAddD(double* p, double v) { unsafeAtomicAdd(p, v); }

// flag==1: external float-typed arrays are bf16; flag==0: they are fp32.
__device__ inline double ldx(const void* p, long i, int isbf) {
  if (isbf) return (double)__bfloat162float(((const bf16*)p)[i]);
  return (double)((const float*)p)[i];
}
__device__ inline void stout(void* p, long i, double v, int isbf) {
  if (isbf) ((bf16*)p)[i] = __float2bfloat16((float)v);
  else ((float*)p)[i] = (float)v;
}

// ---------- dtype detection: bf16 vs fp32 bit-pattern statistics ----------
__global__ void k_detect(const unsigned int* __restrict__ x, int* __restrict__ flag) {
  int tid = threadIdx.x;  // 256
  int cnt = 0;
  for (int j = tid; j < 1024; j += 256) {
    unsigned int u = x[j];
    int e = (u >> 7) & 0xFF;  // exponent field of the LOW u16 viewed as bf16
    cnt += (e >= 100 && e <= 135) ? 1 : 0;
  }
  __shared__ int sh[256];
  sh[tid] = cnt; __syncthreads();
  for (int s = 128; s; s >>= 1) { if (tid < s) sh[tid] += sh[tid + s]; __syncthreads(); }
  if (tid == 0) flag[0] = (sh[0] > 512) ? 1 : 0;
}

// ---------- external -> fp64 convert ----------
__global__ __launch_bounds__(256) void k_convert(const void* __restrict__ x, double* __restrict__ A,
                                                 long n, const int* __restrict__ flag) {
  int isbf = flag[0];
  long i = (long)blockIdx.x * 256 + threadIdx.x;
  if (i < n) A[i] = ldx(x, i, isbf);
}

// ---------- external -> fp32 convert (gather shadow) ----------
__global__ __launch_bounds__(256) void k_convert_f(const void* __restrict__ x, float* __restrict__ hf,
                                                   long n, const int* __restrict__ flag) {
  int isbf = flag[0];
  long i = (long)blockIdx.x * 256 + threadIdx.x;
  if (i < n) hf[i] = (float)ldx(x, i, isbf);
}

// ---------- CSR build: histogram ----------
__global__ __launch_bounds__(256) void k_hist(const int* __restrict__ ei, int* __restrict__ deg) {
  int e = blockIdx.x * 256 + threadIdx.x;
  if (e < N_EDGES) atomicAdd(&deg[ei[N_EDGES + e]], 1);
}

// ---------- CSR build: exclusive scan (1 block) ----------
__global__ void k_scan(const int* __restrict__ deg, int* __restrict__ ofs, int* __restrict__ cursor) {
  __shared__ int sums[256];
  int t = threadIdx.x;
  const int CH = (N_NODES + 255) / 256;
  int lo = t * CH; int hi = lo + CH; if (hi > N_NODES) hi = N_NODES;
  int s = 0;
  for (int i = lo; i < hi; i++) s += deg[i];
  sums[t] = s; __syncthreads();
  if (t == 0) { int run = 0; for (int i = 0; i < 256; i++) { int v = sums[i]; sums[i] = run; run += v; } }
  __syncthreads();
  int run = sums[t];
  for (int i = lo; i < hi; i++) { ofs[i] = run; cursor[i] = run; run += deg[i]; }
  if (t == 255) ofs[N_NODES] = N_EDGES;
}

// ---------- CSR build: fill ----------
__global__ __launch_bounds__(256) void k_fill(const int* __restrict__ ei, int* __restrict__ cursor,
                                              int* __restrict__ csr) {
  int e = blockIdx.x * 256 + threadIdx.x;
  if (e < N_EDGES) {
    int d = ei[N_EDGES + e];
    int p = atomicAdd(&cursor[d], 1);
    csr[p] = ei[e];
  }
}

// ---------- graph offsets from sorted batch (lower_bound per graph) ----------
__global__ void k_gofs(const int* __restrict__ batch, int* __restrict__ gofs) {
  int g = threadIdx.x;  // 512
  int lo = 0, hi = N_NODES;
  while (lo < hi) { int mid = (lo + hi) >> 1; if (batch[mid] < g) lo = mid + 1; else hi = mid; }
  gofs[g] = lo;
  if (g == 0) gofs[NGRAPH] = N_NODES;
}

// ---------- gather: Q[n] = h[n] + sum_{j in in(n)} h[src_j] ----------
// Reads the fp32 shadow hf (halved bytes vs fp64), accumulates fp64.
__global__ __launch_bounds__(256) void k_gather(const float* __restrict__ hf,
                                                const int* __restrict__ ofs,
                                                const int* __restrict__ csr,
                                                double* __restrict__ outQ) {
  int node = blockIdx.x * 4 + (threadIdx.x >> 6);
  int lane = threadIdx.x & 63;
  int beg = ofs[node], end = ofs[node + 1];
  float2 sv = *(const float2*)&hf[(long)node * DIM + lane * 2];
  double accx = (double)sv.x, accy = (double)sv.y;
  int j = beg;
  for (; j + 3 < end; j += 4) {
    int s0 = csr[j], s1 = csr[j + 1], s2 = csr[j + 2], s3 = csr[j + 3];
    float2 v0 = *(const float2*)&hf[(long)s0 * DIM + lane * 2];
    float2 v1 = *(const float2*)&hf[(long)s1 * DIM + lane * 2];
    float2 v2 = *(const float2*)&hf[(long)s2 * DIM + lane * 2];
    float2 v3 = *(const float2*)&hf[(long)s3 * DIM + lane * 2];
    accx += (double)v0.x; accy += (double)v0.y;
    accx += (double)v1.x; accy += (double)v1.y;
    accx += (double)v2.x; accy += (double)v2.y;
    accx += (double)v3.x; accy += (double)v3.y;
  }
  for (; j < end; j++) {
    int s0 = csr[j];
    float2 v0 = *(const float2*)&hf[(long)s0 * DIM + lane * 2];
    accx += (double)v0.x; accy += (double)v0.y;
  }
  *(double2*)&outQ[(long)node * DIM + lane * 2] = make_double2(accx, accy);
}

// ---------- normalize codebooks (fp64) ----------
__global__ void k_cbn(const void* __restrict__ cb, double* __restrict__ cbn, const int* __restrict__ flag) {
  int isbf = flag[0];
  int b = blockIdx.x, d = threadIdx.x;  // 144 blocks x 64 threads
  double v0 = ldx(cb, (long)b * DIM + d, isbf);
  double v1 = ldx(cb, (long)b * DIM + d + 64, isbf);
  double ss = v0 * v0 + v1 * v1;
  for (int o = 32; o; o >>= 1) ss += __shfl_xor(ss, o);
  double inv = 1.0 / sqrt(ss + 1e-12);
  cbn[b * DIM + d] = v0 * inv;
  cbn[b * DIM + d + 64] = v1 * inv;
}

// ---------- Gram matrices per layer ----------
__global__ void k_gram(const double* __restrict__ cbn, double* __restrict__ G) {
  int b = blockIdx.x, t = threadIdx.x;  // 3*48*48 blocks x 64
  int l = b / (48 * 48); int rem = b % (48 * 48); int a = rem / 48, c = rem % 48;
  const double* ra = cbn + (long)(l * 48 + a) * DIM;
  const double* rc = cbn + (long)(l * 48 + c) * DIM;
  double s = ra[t] * rc[t] + ra[t + 64] * rc[t + 64];
  for (int o = 32; o; o >>= 1) s += __shfl_xor(s, o);
  if (t == 0) G[b] = s;
}

// ---------- fp64 GEMM + bias + relu ----------
__global__ __launch_bounds__(256) void k_gemm_relu(const double* __restrict__ in,
                                                   const double* __restrict__ W,
                                                   const double* __restrict__ bias,
                                                   double* __restrict__ out) {
  __shared__ double ul[32 * DIM];
  int tid = threadIdx.x;
  long base = (long)blockIdx.x * 32;
  for (int j = tid; j < 32 * DIM; j += 256) ul[j] = in[base * DIM + j];
  __syncthreads();
  int c = 2 * (tid & 63);
  int tr = tid >> 6;
  double acc[8][2] = {};
  for (int k = 0; k < DIM; k += 2) {
    double2 wa = *(const double2*)&W[k * DIM + c];
    double2 wb = *(const double2*)&W[(k + 1) * DIM + c];
#pragma unroll
    for (int rg = 0; rg < 8; rg++) {
      double2 u = *(const double2*)&ul[(rg * 4 + tr) * DIM + k];
      acc[rg][0] += u.x * wa.x + u.y * wb.x;
      acc[rg][1] += u.x * wa.y + u.y * wb.y;
    }
  }
  double2 bv = *(const double2*)&bias[c];
#pragma unroll
  for (int rg = 0; rg < 8; rg++) {
    double v0 = acc[rg][0] + bv.x;
    double v1 = acc[rg][1] + bv.y;
    v0 = v0 > 0.0 ? v0 : 0.0;
    v1 = v1 > 0.0 ? v1 : 0.0;
    *(double2*)&out[(base + rg * 4 + tr) * DIM + c] = make_double2(v0, v1);
  }
}

// ---------- BN stats ----------
__global__ __launch_bounds__(256) void k_bn_stats(const double* __restrict__ h, double* __restrict__ stats) {
  int tid = threadIdx.x; int col = tid & 127; int half = tid >> 7;
  double s = 0.0, s2 = 0.0;
  for (long r = blockIdx.x * 2 + half; r < N_NODES; r += 2048) {
    double v = h[r * DIM + col];
    s += v; s2 += v * v;
  }
  __shared__ double ls[256], ls2[256];
  ls[tid] = s; ls2[tid] = s2;
  __syncthreads();
  if (tid < 128) {
    atomAddD(&stats[col], ls[tid] + ls[tid + 128]);
    atomAddD(&stats[DIM + col], ls2[tid] + ls2[tid + 128]);
  }
}

// ---------- BN prep ----------
__global__ void k_bn_prep(const double* __restrict__ stats, const void* __restrict__ gamma,
                          const void* __restrict__ beta, double* __restrict__ ss,
                          int l, const int* __restrict__ flag) {
  int isbf = flag[0];
  int d = threadIdx.x;  // 128
  double mean = stats[d] / (double)N_NODES;
  double var = stats[DIM + d] / (double)N_NODES - mean * mean;
  double sc = ldx(gamma, (long)l * DIM + d, isbf) / sqrt(var + 1e-5);
  ss[d] = sc;
  ss[DIM + d] = ldx(beta, (long)l * DIM + d, isbf) - mean * sc;
}

// ---------- normalize in place + xs out + fp32 shadow + ||h||^2 ----------
__global__ __launch_bounds__(256) void k_normalize(double* __restrict__ h, const double* __restrict__ ss,
                                                   void* __restrict__ out, float* __restrict__ hf,
                                                   double* __restrict__ hh,
                                                   int l, const int* __restrict__ flag) {
  int isbf = flag[0];
  int tid = threadIdx.x;
  int n = blockIdx.x * 2 + (tid >> 7);
  int d = tid & 127;
  double v = h[(long)n * DIM + d] * ss[d] + ss[DIM + d];
  h[(long)n * DIM + d] = v;
  hf[(long)n * DIM + d] = (float)v;
  const long XS_BASE = (long)NGRAPH * DIM * NLAY;
  stout(out, XS_BASE + (long)n * (DIM * NLAY) + l * DIM + d, v, isbf);
  double s2 = v * v;
  for (int o = 32; o; o >>= 1) s2 += __shfl_xor(s2, o);
  __shared__ double wp[4];
  if ((tid & 63) == 0) wp[tid >> 6] = s2;
  __syncthreads();
  if (tid == 0) hh[n] = wp[0] + wp[1];
  else if (tid == 128) hh[n] = wp[2] + wp[3];
}

// ---------- xpool: segmented sum per graph (no atomics; batch sorted) ----------
__global__ __launch_bounds__(256) void k_xpool(const double* __restrict__ h, const int* __restrict__ gofs,
                                               double* __restrict__ xpool, int l) {
  int g = blockIdx.x;
  int tid = threadIdx.x;
  int d = tid & 127, half = tid >> 7;
  int beg = gofs[g], end = gofs[g + 1];
  double acc = 0.0;
  for (int n = beg + half; n < end; n += 2) acc += h[(long)n * DIM + d];
  __shared__ double sh[256];
  sh[tid] = acc; __syncthreads();
  if (tid < 128) xpool[(long)g * (DIM * NLAY) + l * DIM + tid] = sh[tid] + sh[tid + 128];
}

// ---------- dotH = h_norm @ cbn^T (48 cols), fp64 compute, fp32 store ----------
__global__ __launch_bounds__(256) void k_dotH(const double* __restrict__ hn,
                                              const double* __restrict__ cbnL,
                                              float* __restrict__ dH) {
  __shared__ double cl[48 * 134];
  int tid = threadIdx.x;
  for (int j = tid; j < 48 * DIM; j += 256) { int c = j >> 7, k = j & 127; cl[c * 134 + k] = cbnL[j]; }
  __syncthreads();
  int ct = tid & 7; int c0 = ct * 6; int rt = tid >> 3;
  long r0 = (long)blockIdx.x * 64 + rt; long r1 = r0 + 32;
  long r0c = r0 < N_NODES ? r0 : (N_NODES - 1);
  long r1c = r1 < N_NODES ? r1 : (N_NODES - 1);
  double acc0[6] = {}, acc1[6] = {};
  for (int k = 0; k < DIM; k += 2) {
    double2 h0 = *(const double2*)&hn[r0c * DIM + k];
    double2 h1 = *(const double2*)&hn[r1c * DIM + k];
#pragma unroll
    for (int j = 0; j < 6; j++) {
      double2 cv = *(const double2*)&cl[(c0 + j) * 134 + k];
      acc0[j] += h0.x * cv.x + h0.y * cv.y;
      acc1[j] += h1.x * cv.x + h1.y * cv.y;
    }
  }
  if (r0 < N_NODES) {
#pragma unroll
    for (int j = 0; j < 6; j++) dH[r0 * 48 + c0 + j] = (float)acc0[j];
  }
  if (r1 < N_NODES) {
#pragma unroll
    for (int j = 0; j < 6; j++) dH[r1 * 48 + c0 + j] = (float)acc1[j];
  }
}

// ---------- VQ select via dotH & Gram; ids + commit ----------
__global__ __launch_bounds__(256) void k_vq(const float* __restrict__ dH, const double* __restrict__ hh,
                                            const double* __restrict__ G, void* __restrict__ out,
                                            double* __restrict__ commit, int l, const int* __restrict__ flag) {
  int isbf = flag[0];
  __shared__ double Gl[48 * 48];
  int tid = threadIdx.x;
  for (int j = tid; j < 48 * 48; j += 256) Gl[j] = G[j];
  __syncthreads();
  long n = (long)blockIdx.x * 256 + tid;
  double csum = 0.0;
  if (n < N_NODES) {
    double dh[48];
#pragma unroll
    for (int c = 0; c < 48; c++) dh[c] = (double)dH[n * 48 + c];
    int i0 = 0; double b0 = dh[0];
#pragma unroll
    for (int c = 1; c < 16; c++) { if (dh[c] > b0) { b0 = dh[c]; i0 = c; } }
    int i1 = 0; double b1 = dh[16] - Gl[i0 * 48 + 16];
#pragma unroll
    for (int c = 1; c < 16; c++) {
      double s = dh[16 + c] - Gl[i0 * 48 + 16 + c];
      if (s > b1) { b1 = s; i1 = c; }
    }
    int i2 = 0; double b2 = dh[32] - Gl[i0 * 48 + 32] - Gl[(16 + i1) * 48 + 32];
#pragma unroll
    for (int c = 1; c < 16; c++) {
      double s = dh[32 + c] - Gl[i0 * 48 + 32 + c] - Gl[(16 + i1) * 48 + 32 + c];
      if (s > b2) { b2 = s; i2 = c; }
    }
    double r1s = hh[n] - 2.0 * b0 + Gl[i0 * 48 + i0];
    double r2s = r1s - 2.0 * b1 + Gl[(16 + i1) * 48 + 16 + i1];
    double r3s = r2s - 2.0 * b2 + Gl[(32 + i2) * 48 + 32 + i2];
    csum = r1s + r2s + r3s;
    const long IDS_BASE = (long)NGRAPH * DIM * NLAY + (long)N_NODES * DIM * NLAY + 1;
    long base = IDS_BASE + n * (NLAY * NRES) + l * NRES;
    stout(out, base + 0, (double)i0, isbf);
    stout(out, base + 1, (double)i1, isbf);
    stout(out, base + 2, (double)i2, isbf);
  }
  for (int o = 32; o; o >>= 1) csum += __shfl_xor(csum, o);
  if ((tid & 63) == 0 && csum != 0.0) atomAddD(commit, csum);
}

// ---------- final: xpool + commit -> out ----------
__global__ __launch_bounds__(256) void k_out(const double* __restrict__ xpool, const double* __restrict__ commit,
                                             void* __restrict__ out, const int* __restrict__ flag) {
  int isbf = flag[0];
  long i = (long)blockIdx.x * 256 + threadIdx.x;
  const long NP = (long)NGRAPH * DIM * NLAY;
  if (i < NP) {
    stout(out, i, xpool[i], isbf);
  } else if (i == NP) {
    double c = commit[0] * (0.25 / ((double)N_NODES * (double)DIM));
    stout(out, NP + (long)N_NODES * DIM * NLAY, c, isbf);
  }
}

extern "C" void kernel_launch(void* const* d_in, const int* in_sizes, int n_in,
                              void* d_out, int out_size, void* d_ws, size_t ws_size,
                              hipStream_t stream) {
  const void* x = d_in[0];
  const int* ei = (const int*)d_in[1];
  const int* batch = (const int*)d_in[2];
  const void* W1 = d_in[3];
  const void* b1 = d_in[4];
  const void* W2 = d_in[5];
  const void* b2 = d_in[6];
  const void* gamma = d_in[7];
  const void* beta = d_in[8];
  const void* cb = d_in[9];

  double* w = (double*)d_ws;
  double* A = w;                        // 12,800,000
  double* B = A + 12800000;             // 12,800,000
  double* cbn = B + 12800000;           // 18,432
  double* G = cbn + 18432;              // 6,912
  double* stats = G + 6912;             // 256
  double* ss = stats + 256;             // 256
  double* hh = ss + 256;                // 100,000
  double* xpool = hh + N_NODES;         // 196,608
  double* commit = xpool + (long)NGRAPH * DIM * NLAY;  // 1
  double* W1d = commit + 1;             // 49,152
  double* W2d = W1d + 49152;            // 49,152
  double* b1d = W2d + 49152;            // 384
  double* b2d = b1d + 384;              // 384
  float* fbuf = (float*)(b2d + 384);
  float* dH = fbuf;                     // 4,800,000 floats
  float* hf = dH + (long)N_NODES * 48;  // 12,800,000 floats
  int* ibuf = (int*)(hf + 12800000);
  int* flag = ibuf;                     // 1 (+pad)
  int* deg = ibuf + 64;                 // N_NODES
  int* ofs = deg + N_NODES;             // N_NODES + 1
  int* cursor = ofs + N_NODES + 1;      // N_NODES
  int* csr = cursor + N_NODES;          // N_EDGES
  int* gofs = csr + N_EDGES;            // NGRAPH + 1

  k_detect<<<1, 256, 0, stream>>>((const unsigned int*)x, flag);
  // zero accumulators (xpool + commit contiguous)
  hipMemsetAsync(xpool, 0, ((long)NGRAPH * DIM * NLAY + 1) * sizeof(double), stream);
  hipMemsetAsync(deg, 0, N_NODES * sizeof(int), stream);
  // fp32 shadow of x for the gather (no fp64 x copy needed anymore)
  k_convert_f<<<50000, 256, 0, stream>>>(x, hf, (long)N_NODES * DIM, flag);
  k_convert<<<192, 256, 0, stream>>>(W1, W1d, 49152, flag);
  k_convert<<<192, 256, 0, stream>>>(W2, W2d, 49152, flag);
  k_convert<<<2, 256, 0, stream>>>(b1, b1d, 384, flag);
  k_convert<<<2, 256, 0, stream>>>(b2, b2d, 384, flag);
  k_cbn<<<NLAY * NRES * NCODE, 64, 0, stream>>>(cb, cbn, flag);
  k_gram<<<NLAY * 48 * 48, 64, 0, stream>>>(cbn, G);
  // CSR build (once; reused all 3 layers)
  k_hist<<<(N_EDGES + 255) / 256, 256, 0, stream>>>(ei, deg);
  k_scan<<<1, 256, 0, stream>>>(deg, ofs, cursor);
  k_fill<<<(N_EDGES + 255) / 256, 256, 0, stream>>>(ei, cursor, csr);
  k_gofs<<<1, NGRAPH, 0, stream>>>(batch, gofs);

  double* P = A; double* Q = B;
  for (int l = 0; l < NLAY; l++) {
    k_gather<<<N_NODES / 4, 256, 0, stream>>>(hf, ofs, csr, Q);
    k_gemm_relu<<<3125, 256, 0, stream>>>(Q, W1d + l * DIM * DIM, b1d + l * DIM, P);
    k_gemm_relu<<<3125, 256, 0, stream>>>(P, W2d + l * DIM * DIM, b2d + l * DIM, Q);
    hipMemsetAsync(stats, 0, 256 * sizeof(double), stream);
    k_bn_stats<<<1024, 256, 0, stream>>>(Q, stats);
    k_bn_prep<<<1, 128, 0, stream>>>(stats, gamma, beta, ss, l, flag);
    k_normalize<<<50000, 256, 0, stream>>>(Q, ss, d_out, hf, hh, l, flag);
    k_xpool<<<NGRAPH, 256, 0, stream>>>(Q, gofs, xpool, l);
    k_dotH<<<1563, 256, 0, stream>>>(Q, cbn + (long)l * 48 * DIM, dH);
    k_vq<<<391, 256, 0, stream>>>(dH, hh, G + l * 48 * 48, d_out, commit, l, flag);
    double* t = P; P = Q; Q = t;
  }
  k_out<<<769, 256, 0, stream>>>(xpool, commit, d_out, flag);
}

// Round 2
// 2263.717 us; speedup vs baseline: 1.2943x; 1.1050x over previous
//
#include <hip/hip_runtime.h>
#include <hip/hip_bf16.h>

#define N_NODES 100000
#define N_EDGES 1600000
#define DIM 128
#define NLAY 3
#define NRES 3
#define NCODE 16
#define NGRAPH 512
#define SCAN_NB ((N_NODES + 255) / 256)  // 391

using bf16 = __hip_bfloat16;

__device__ inline void atomAddD(double* p, double v) { unsafeAtomicAdd(p, v); }

// flag==1: external float-typed arrays are bf16; flag==0: they are fp32.
__device__ inline double ldx(const void* p, long i, int isbf) {
  if (isbf) return (double)__bfloat162float(((const bf16*)p)[i]);
  return (double)((const float*)p)[i];
}
__device__ inline void stout(void* p, long i, double v, int isbf) {
  if (isbf) ((bf16*)p)[i] = __float2bfloat16((float)v);
  else ((float*)p)[i] = (float)v;
}

// ---------- dtype detection: bf16 vs fp32 bit-pattern statistics ----------
__global__ void k_detect(const unsigned int* __restrict__ x, int* __restrict__ flag) {
  int tid = threadIdx.x;  // 256
  int cnt = 0;
  for (int j = tid; j < 1024; j += 256) {
    unsigned int u = x[j];
    int e = (u >> 7) & 0xFF;  // exponent field of the LOW u16 viewed as bf16
    cnt += (e >= 100 && e <= 135) ? 1 : 0;
  }
  __shared__ int sh[256];
  sh[tid] = cnt; __syncthreads();
  for (int s = 128; s; s >>= 1) { if (tid < s) sh[tid] += sh[tid + s]; __syncthreads(); }
  if (tid == 0) flag[0] = (sh[0] > 512) ? 1 : 0;
}

// ---------- external -> fp64 convert ----------
__global__ __launch_bounds__(256) void k_convert(const void* __restrict__ x, double* __restrict__ A,
                                                 long n, const int* __restrict__ flag) {
  int isbf = flag[0];
  long i = (long)blockIdx.x * 256 + threadIdx.x;
  if (i < n) A[i] = ldx(x, i, isbf);
}

// ---------- external -> fp32 convert (gather shadow) ----------
__global__ __launch_bounds__(256) void k_convert_f(const void* __restrict__ x, float* __restrict__ hf,
                                                   long n, const int* __restrict__ flag) {
  int isbf = flag[0];
  long i = (long)blockIdx.x * 256 + threadIdx.x;
  if (i < n) hf[i] = (float)ldx(x, i, isbf);
}

// ---------- CSR build: histogram ----------
__global__ __launch_bounds__(256) void k_hist(const int* __restrict__ ei, int* __restrict__ deg) {
  int e = blockIdx.x * 256 + threadIdx.x;
  if (e < N_EDGES) atomicAdd(&deg[ei[N_EDGES + e]], 1);
}

// ---------- CSR build: hierarchical exclusive scan (3 phases, all parallel) ----------
// Phase 1: per-block (256-chunk) sums of deg.
__global__ __launch_bounds__(256) void k_scan1(const int* __restrict__ deg, int* __restrict__ bsum) {
  int i = blockIdx.x * 256 + threadIdx.x;
  int v = (i < N_NODES) ? deg[i] : 0;
  for (int o = 32; o; o >>= 1) v += __shfl_xor(v, o);
  __shared__ int sh[4];
  if ((threadIdx.x & 63) == 0) sh[threadIdx.x >> 6] = v;
  __syncthreads();
  if (threadIdx.x == 0) bsum[blockIdx.x] = sh[0] + sh[1] + sh[2] + sh[3];
}

// Phase 2: exclusive scan of the SCAN_NB block sums (single tiny block).
__global__ void k_scan2(int* __restrict__ bsum) {
  __shared__ int sh[512];
  int t = threadIdx.x;
  int v = (t < SCAN_NB) ? bsum[t] : 0;
  sh[t] = v; __syncthreads();
  for (int s = 1; s < 512; s <<= 1) {
    int add = (t >= s) ? sh[t - s] : 0;
    __syncthreads();
    sh[t] += add;
    __syncthreads();
  }
  if (t < SCAN_NB) bsum[t] = sh[t] - v;  // exclusive
}

// Phase 3: in-block scan + block offset -> ofs/cursor.
__global__ __launch_bounds__(256) void k_scan3(const int* __restrict__ deg, const int* __restrict__ bsum,
                                               int* __restrict__ ofs, int* __restrict__ cursor) {
  int t = threadIdx.x;
  int i = blockIdx.x * 256 + t;
  int v = (i < N_NODES) ? deg[i] : 0;
  __shared__ int sh[256];
  sh[t] = v; __syncthreads();
  for (int s = 1; s < 256; s <<= 1) {
    int add = (t >= s) ? sh[t - s] : 0;
    __syncthreads();
    sh[t] += add;
    __syncthreads();
  }
  int excl = sh[t] - v + bsum[blockIdx.x];
  if (i < N_NODES) { ofs[i] = excl; cursor[i] = excl; }
  if (i == N_NODES - 1) ofs[N_NODES] = excl + v;
}

// ---------- CSR build: fill ----------
__global__ __launch_bounds__(256) void k_fill(const int* __restrict__ ei, int* __restrict__ cursor,
                                              int* __restrict__ csr) {
  int e = blockIdx.x * 256 + threadIdx.x;
  if (e < N_EDGES) {
    int d = ei[N_EDGES + e];
    int p = atomicAdd(&cursor[d], 1);
    csr[p] = ei[e];
  }
}

// ---------- graph offsets from sorted batch (lower_bound per graph) ----------
__global__ void k_gofs(const int* __restrict__ batch, int* __restrict__ gofs) {
  int g = threadIdx.x;  // 512
  int lo = 0, hi = N_NODES;
  while (lo < hi) { int mid = (lo + hi) >> 1; if (batch[mid] < g) lo = mid + 1; else hi = mid; }
  gofs[g] = lo;
  if (g == 0) gofs[NGRAPH] = N_NODES;
}

// ---------- gather: Q[n] = h[n] + sum_{j in in(n)} h[src_j] ----------
// Reads the fp32 shadow hf (halved bytes vs fp64), accumulates fp64.
__global__ __launch_bounds__(256) void k_gather(const float* __restrict__ hf,
                                                const int* __restrict__ ofs,
                                                const int* __restrict__ csr,
                                                double* __restrict__ outQ) {
  int node = blockIdx.x * 4 + (threadIdx.x >> 6);
  int lane = threadIdx.x & 63;
  int beg = ofs[node], end = ofs[node + 1];
  float2 sv = *(const float2*)&hf[(long)node * DIM + lane * 2];
  double accx = (double)sv.x, accy = (double)sv.y;
  int j = beg;
  for (; j + 3 < end; j += 4) {
    int s0 = csr[j], s1 = csr[j + 1], s2 = csr[j + 2], s3 = csr[j + 3];
    float2 v0 = *(const float2*)&hf[(long)s0 * DIM + lane * 2];
    float2 v1 = *(const float2*)&hf[(long)s1 * DIM + lane * 2];
    float2 v2 = *(const float2*)&hf[(long)s2 * DIM + lane * 2];
    float2 v3 = *(const float2*)&hf[(long)s3 * DIM + lane * 2];
    accx += (double)v0.x; accy += (double)v0.y;
    accx += (double)v1.x; accy += (double)v1.y;
    accx += (double)v2.x; accy += (double)v2.y;
    accx += (double)v3.x; accy += (double)v3.y;
  }
  for (; j < end; j++) {
    int s0 = csr[j];
    float2 v0 = *(const float2*)&hf[(long)s0 * DIM + lane * 2];
    accx += (double)v0.x; accy += (double)v0.y;
  }
  *(double2*)&outQ[(long)node * DIM + lane * 2] = make_double2(accx, accy);
}

// ---------- normalize codebooks (fp64) ----------
__global__ void k_cbn(const void* __restrict__ cb, double* __restrict__ cbn, const int* __restrict__ flag) {
  int isbf = flag[0];
  int b = blockIdx.x, d = threadIdx.x;  // 144 blocks x 64 threads
  double v0 = ldx(cb, (long)b * DIM + d, isbf);
  double v1 = ldx(cb, (long)b * DIM + d + 64, isbf);
  double ss = v0 * v0 + v1 * v1;
  for (int o = 32; o; o >>= 1) ss += __shfl_xor(ss, o);
  double inv = 1.0 / sqrt(ss + 1e-12);
  cbn[b * DIM + d] = v0 * inv;
  cbn[b * DIM + d + 64] = v1 * inv;
}

// ---------- Gram matrices per layer ----------
__global__ void k_gram(const double* __restrict__ cbn, double* __restrict__ G) {
  int b = blockIdx.x, t = threadIdx.x;  // 3*48*48 blocks x 64
  int l = b / (48 * 48); int rem = b % (48 * 48); int a = rem / 48, c = rem % 48;
  const double* ra = cbn + (long)(l * 48 + a) * DIM;
  const double* rc = cbn + (long)(l * 48 + c) * DIM;
  double s = ra[t] * rc[t] + ra[t + 64] * rc[t + 64];
  for (int o = 32; o; o >>= 1) s += __shfl_xor(s, o);
  if (t == 0) G[b] = s;
}

// ---------- fp64 GEMM + bias + relu ----------
__global__ __launch_bounds__(256) void k_gemm_relu(const double* __restrict__ in,
                                                   const double* __restrict__ W,
                                                   const double* __restrict__ bias,
                                                   double* __restrict__ out) {
  __shared__ double ul[32 * DIM];
  int tid = threadIdx.x;
  long base = (long)blockIdx.x * 32;
  for (int j = tid; j < 32 * DIM; j += 256) ul[j] = in[base * DIM + j];
  __syncthreads();
  int c = 2 * (tid & 63);
  int tr = tid >> 6;
  double acc[8][2] = {};
  for (int k = 0; k < DIM; k += 2) {
    double2 wa = *(const double2*)&W[k * DIM + c];
    double2 wb = *(const double2*)&W[(k + 1) * DIM + c];
#pragma unroll
    for (int rg = 0; rg < 8; rg++) {
      double2 u = *(const double2*)&ul[(rg * 4 + tr) * DIM + k];
      acc[rg][0] += u.x * wa.x + u.y * wb.x;
      acc[rg][1] += u.x * wa.y + u.y * wb.y;
    }
  }
  double2 bv = *(const double2*)&bias[c];
#pragma unroll
  for (int rg = 0; rg < 8; rg++) {
    double v0 = acc[rg][0] + bv.x;
    double v1 = acc[rg][1] + bv.y;
    v0 = v0 > 0.0 ? v0 : 0.0;
    v1 = v1 > 0.0 ? v1 : 0.0;
    *(double2*)&out[(base + rg * 4 + tr) * DIM + c] = make_double2(v0, v1);
  }
}

// ---------- BN stats ----------
__global__ __launch_bounds__(256) void k_bn_stats(const double* __restrict__ h, double* __restrict__ stats) {
  int tid = threadIdx.x; int col = tid & 127; int half = tid >> 7;
  double s = 0.0, s2 = 0.0;
  for (long r = blockIdx.x * 2 + half; r < N_NODES; r += 2048) {
    double v = h[r * DIM + col];
    s += v; s2 += v * v;
  }
  __shared__ double ls[256], ls2[256];
  ls[tid] = s; ls2[tid] = s2;
  __syncthreads();
  if (tid < 128) {
    atomAddD(&stats[col], ls[tid] + ls[tid + 128]);
    atomAddD(&stats[DIM + col], ls2[tid] + ls2[tid + 128]);
  }
}

// ---------- BN prep ----------
__global__ void k_bn_prep(const double* __restrict__ stats, const void* __restrict__ gamma,
                          const void* __restrict__ beta, double* __restrict__ ss,
                          int l, const int* __restrict__ flag) {
  int isbf = flag[0];
  int d = threadIdx.x;  // 128
  double mean = stats[d] / (double)N_NODES;
  double var = stats[DIM + d] / (double)N_NODES - mean * mean;
  double sc = ldx(gamma, (long)l * DIM + d, isbf) / sqrt(var + 1e-5);
  ss[d] = sc;
  ss[DIM + d] = ldx(beta, (long)l * DIM + d, isbf) - mean * sc;
}

// ---------- normalize in place + xs out + fp32 shadow + ||h||^2 ----------
__global__ __launch_bounds__(256) void k_normalize(double* __restrict__ h, const double* __restrict__ ss,
                                                   void* __restrict__ out, float* __restrict__ hf,
                                                   double* __restrict__ hh,
                                                   int l, const int* __restrict__ flag) {
  int isbf = flag[0];
  int tid = threadIdx.x;
  int n = blockIdx.x * 2 + (tid >> 7);
  int d = tid & 127;
  double v = h[(long)n * DIM + d] * ss[d] + ss[DIM + d];
  h[(long)n * DIM + d] = v;
  hf[(long)n * DIM + d] = (float)v;
  const long XS_BASE = (long)NGRAPH * DIM * NLAY;
  stout(out, XS_BASE + (long)n * (DIM * NLAY) + l * DIM + d, v, isbf);
  double s2 = v * v;
  for (int o = 32; o; o >>= 1) s2 += __shfl_xor(s2, o);
  __shared__ double wp[4];
  if ((tid & 63) == 0) wp[tid >> 6] = s2;
  __syncthreads();
  if (tid == 0) hh[n] = wp[0] + wp[1];
  else if (tid == 128) hh[n] = wp[2] + wp[3];
}

// ---------- xpool: segmented sum per graph (no atomics; batch sorted) ----------
__global__ __launch_bounds__(256) void k_xpool(const double* __restrict__ h, const int* __restrict__ gofs,
                                               double* __restrict__ xpool, int l) {
  int g = blockIdx.x;
  int tid = threadIdx.x;
  int d = tid & 127, half = tid >> 7;
  int beg = gofs[g], end = gofs[g + 1];
  double acc = 0.0;
  for (int n = beg + half; n < end; n += 2) acc += h[(long)n * DIM + d];
  __shared__ double sh[256];
  sh[tid] = acc; __syncthreads();
  if (tid < 128) xpool[(long)g * (DIM * NLAY) + l * DIM + tid] = sh[tid] + sh[tid + 128];
}

// ---------- dotH = h_norm @ cbn^T (48 cols), fp64 compute, fp32 store ----------
__global__ __launch_bounds__(256) void k_dotH(const double* __restrict__ hn,
                                              const double* __restrict__ cbnL,
                                              float* __restrict__ dH) {
  __shared__ double cl[48 * 134];
  int tid = threadIdx.x;
  for (int j = tid; j < 48 * DIM; j += 256) { int c = j >> 7, k = j & 127; cl[c * 134 + k] = cbnL[j]; }
  __syncthreads();
  int ct = tid & 7; int c0 = ct * 6; int rt = tid >> 3;
  long r0 = (long)blockIdx.x * 64 + rt; long r1 = r0 + 32;
  long r0c = r0 < N_NODES ? r0 : (N_NODES - 1);
  long r1c = r1 < N_NODES ? r1 : (N_NODES - 1);
  double acc0[6] = {}, acc1[6] = {};
  for (int k = 0; k < DIM; k += 2) {
    double2 h0 = *(const double2*)&hn[r0c * DIM + k];
    double2 h1 = *(const double2*)&hn[r1c * DIM + k];
#pragma unroll
    for (int j = 0; j < 6; j++) {
      double2 cv = *(const double2*)&cl[(c0 + j) * 134 + k];
      acc0[j] += h0.x * cv.x + h0.y * cv.y;
      acc1[j] += h1.x * cv.x + h1.y * cv.y;
    }
  }
  if (r0 < N_NODES) {
#pragma unroll
    for (int j = 0; j < 6; j++) dH[r0 * 48 + c0 + j] = (float)acc0[j];
  }
  if (r1 < N_NODES) {
#pragma unroll
    for (int j = 0; j < 6; j++) dH[r1 * 48 + c0 + j] = (float)acc1[j];
  }
}

// ---------- VQ select via dotH & Gram; ids + commit ----------
__global__ __launch_bounds__(256) void k_vq(const float* __restrict__ dH, const double* __restrict__ hh,
                                            const double* __restrict__ G, void* __restrict__ out,
                                            double* __restrict__ commit, int l, const int* __restrict__ flag) {
  int isbf = flag[0];
  __shared__ double Gl[48 * 48];
  int tid = threadIdx.x;
  for (int j = tid; j < 48 * 48; j += 256) Gl[j] = G[j];
  __syncthreads();
  long n = (long)blockIdx.x * 256 + tid;
  double csum = 0.0;
  if (n < N_NODES) {
    double dh[48];
#pragma unroll
    for (int c = 0; c < 48; c++) dh[c] = (double)dH[n * 48 + c];
    int i0 = 0; double b0 = dh[0];
#pragma unroll
    for (int c = 1; c < 16; c++) { if (dh[c] > b0) { b0 = dh[c]; i0 = c; } }
    int i1 = 0; double b1 = dh[16] - Gl[i0 * 48 + 16];
#pragma unroll
    for (int c = 1; c < 16; c++) {
      double s = dh[16 + c] - Gl[i0 * 48 + 16 + c];
      if (s > b1) { b1 = s; i1 = c; }
    }
    int i2 = 0; double b2 = dh[32] - Gl[i0 * 48 + 32] - Gl[(16 + i1) * 48 + 32];
#pragma unroll
    for (int c = 1; c < 16; c++) {
      double s = dh[32 + c] - Gl[i0 * 48 + 32 + c] - Gl[(16 + i1) * 48 + 32 + c];
      if (s > b2) { b2 = s; i2 = c; }
    }
    double r1s = hh[n] - 2.0 * b0 + Gl[i0 * 48 + i0];
    double r2s = r1s - 2.0 * b1 + Gl[(16 + i1) * 48 + 16 + i1];
    double r3s = r2s - 2.0 * b2 + Gl[(32 + i2) * 48 + 32 + i2];
    csum = r1s + r2s + r3s;
    const long IDS_BASE = (long)NGRAPH * DIM * NLAY + (long)N_NODES * DIM * NLAY + 1;
    long base = IDS_BASE + n * (NLAY * NRES) + l * NRES;
    stout(out, base + 0, (double)i0, isbf);
    stout(out, base + 1, (double)i1, isbf);
    stout(out, base + 2, (double)i2, isbf);
  }
  for (int o = 32; o; o >>= 1) csum += __shfl_xor(csum, o);
  if ((tid & 63) == 0 && csum != 0.0) atomAddD(commit, csum);
}

// ---------- final: xpool + commit -> out ----------
__global__ __launch_bounds__(256) void k_out(const double* __restrict__ xpool, const double* __restrict__ commit,
                                             void* __restrict__ out, const int* __restrict__ flag) {
  int isbf = flag[0];
  long i = (long)blockIdx.x * 256 + threadIdx.x;
  const long NP = (long)NGRAPH * DIM * NLAY;
  if (i < NP) {
    stout(out, i, xpool[i], isbf);
  } else if (i == NP) {
    double c = commit[0] * (0.25 / ((double)N_NODES * (double)DIM));
    stout(out, NP + (long)N_NODES * DIM * NLAY, c, isbf);
  }
}

extern "C" void kernel_launch(void* const* d_in, const int* in_sizes, int n_in,
                              void* d_out, int out_size, void* d_ws, size_t ws_size,
                              hipStream_t stream) {
  const void* x = d_in[0];
  const int* ei = (const int*)d_in[1];
  const int* batch = (const int*)d_in[2];
  const void* W1 = d_in[3];
  const void* b1 = d_in[4];
  const void* W2 = d_in[5];
  const void* b2 = d_in[6];
  const void* gamma = d_in[7];
  const void* beta = d_in[8];
  const void* cb = d_in[9];

  double* w = (double*)d_ws;
  double* A = w;                        // 12,800,000
  double* B = A + 12800000;             // 12,800,000
  double* cbn = B + 12800000;           // 18,432
  double* G = cbn + 18432;              // 6,912
  double* stats = G + 6912;             // 256
  double* ss = stats + 256;             // 256
  double* hh = ss + 256;                // 100,000
  double* xpool = hh + N_NODES;         // 196,608
  double* commit = xpool + (long)NGRAPH * DIM * NLAY;  // 1
  double* W1d = commit + 1;             // 49,152
  double* W2d = W1d + 49152;            // 49,152
  double* b1d = W2d + 49152;            // 384
  double* b2d = b1d + 384;              // 384
  float* fbuf = (float*)(b2d + 384);
  float* dH = fbuf;                     // 4,800,000 floats
  float* hf = dH + (long)N_NODES * 48;  // 12,800,000 floats
  int* ibuf = (int*)(hf + 12800000);
  int* flag = ibuf;                     // 1 (+pad)
  int* deg = ibuf + 64;                 // N_NODES
  int* ofs = deg + N_NODES;             // N_NODES + 1
  int* cursor = ofs + N_NODES + 1;      // N_NODES
  int* csr = cursor + N_NODES;          // N_EDGES
  int* gofs = csr + N_EDGES;            // NGRAPH + 1
  int* bsum = gofs + NGRAPH + 2;        // SCAN_NB (391)

  k_detect<<<1, 256, 0, stream>>>((const unsigned int*)x, flag);
  // zero accumulators (xpool + commit contiguous)
  hipMemsetAsync(xpool, 0, ((long)NGRAPH * DIM * NLAY + 1) * sizeof(double), stream);
  hipMemsetAsync(deg, 0, N_NODES * sizeof(int), stream);
  // fp32 shadow of x for the gather (no fp64 x copy needed anymore)
  k_convert_f<<<50000, 256, 0, stream>>>(x, hf, (long)N_NODES * DIM, flag);
  k_convert<<<192, 256, 0, stream>>>(W1, W1d, 49152, flag);
  k_convert<<<192, 256, 0, stream>>>(W2, W2d, 49152, flag);
  k_convert<<<2, 256, 0, stream>>>(b1, b1d, 384, flag);
  k_convert<<<2, 256, 0, stream>>>(b2, b2d, 384, flag);
  k_cbn<<<NLAY * NRES * NCODE, 64, 0, stream>>>(cb, cbn, flag);
  k_gram<<<NLAY * 48 * 48, 64, 0, stream>>>(cbn, G);
  // CSR build (once; reused all 3 layers)
  k_hist<<<(N_EDGES + 255) / 256, 256, 0, stream>>>(ei, deg);
  k_scan1<<<SCAN_NB, 256, 0, stream>>>(deg, bsum);
  k_scan2<<<1, 512, 0, stream>>>(bsum);
  k_scan3<<<SCAN_NB, 256, 0, stream>>>(deg, bsum, ofs, cursor);
  k_fill<<<(N_EDGES + 255) / 256, 256, 0, stream>>>(ei, cursor, csr);
  k_gofs<<<1, NGRAPH, 0, stream>>>(batch, gofs);

  double* P = A; double* Q = B;
  for (int l = 0; l < NLAY; l++) {
    k_gather<<<N_NODES / 4, 256, 0, stream>>>(hf, ofs, csr, Q);
    k_gemm_relu<<<3125, 256, 0, stream>>>(Q, W1d + l * DIM * DIM, b1d + l * DIM, P);
    k_gemm_relu<<<3125, 256, 0, stream>>>(P, W2d + l * DIM * DIM, b2d + l * DIM, Q);
    hipMemsetAsync(stats, 0, 256 * sizeof(double), stream);
    k_bn_stats<<<1024, 256, 0, stream>>>(Q, stats);
    k_bn_prep<<<1, 128, 0, stream>>>(stats, gamma, beta, ss, l, flag);
    k_normalize<<<50000, 256, 0, stream>>>(Q, ss, d_out, hf, hh, l, flag);
    k_xpool<<<NGRAPH, 256, 0, stream>>>(Q, gofs, xpool, l);
    k_dotH<<<1563, 256, 0, stream>>>(Q, cbn + (long)l * 48 * DIM, dH);
    k_vq<<<391, 256, 0, stream>>>(dH, hh, G + l * 48 * 48, d_out, commit, l, flag);
    double* t = P; P = Q; Q = t;
  }
  k_out<<<769, 256, 0, stream>>>(xpool, commit, d_out, flag);
}

// Round 3
// 1782.592 us; speedup vs baseline: 1.6437x; 1.2699x over previous
//
#include <hip/hip_runtime.h>
#include <hip/hip_bf16.h>

#define N_NODES 100000
#define N_EDGES 1600000
#define DIM 128
#define NLAY 3
#define NRES 3
#define NCODE 16
#define NGRAPH 512
#define SCAN_NB ((N_NODES + 255) / 256)  // 391
#define GEMM_NB ((N_NODES + 63) / 64)    // 1563

using bf16 = __hip_bfloat16;

__device__ inline void atomAddD(double* p, double v) { unsafeAtomicAdd(p, v); }

// flag==1: external float-typed arrays are bf16; flag==0: they are fp32.
__device__ inline double ldx(const void* p, long i, int isbf) {
  if (isbf) return (double)__bfloat162float(((const bf16*)p)[i]);
  return (double)((const float*)p)[i];
}
__device__ inline void stout(void* p, long i, double v, int isbf) {
  if (isbf) ((bf16*)p)[i] = __float2bfloat16((float)v);
  else ((float*)p)[i] = (float)v;
}

// ---------- dtype detection: bf16 vs fp32 bit-pattern statistics ----------
__global__ void k_detect(const unsigned int* __restrict__ x, int* __restrict__ flag) {
  int tid = threadIdx.x;  // 256
  int cnt = 0;
  for (int j = tid; j < 1024; j += 256) {
    unsigned int u = x[j];
    int e = (u >> 7) & 0xFF;  // exponent field of the LOW u16 viewed as bf16
    cnt += (e >= 100 && e <= 135) ? 1 : 0;
  }
  __shared__ int sh[256];
  sh[tid] = cnt; __syncthreads();
  for (int s = 128; s; s >>= 1) { if (tid < s) sh[tid] += sh[tid + s]; __syncthreads(); }
  if (tid == 0) flag[0] = (sh[0] > 512) ? 1 : 0;
}

// ---------- external -> fp32 convert ----------
__global__ __launch_bounds__(256) void k_convert_f(const void* __restrict__ x, float* __restrict__ hf,
                                                   long n, const int* __restrict__ flag) {
  int isbf = flag[0];
  long i = (long)blockIdx.x * 256 + threadIdx.x;
  if (i < n) hf[i] = (float)ldx(x, i, isbf);
}

// ---------- CSR build: histogram ----------
__global__ __launch_bounds__(256) void k_hist(const int* __restrict__ ei, int* __restrict__ deg) {
  int e = blockIdx.x * 256 + threadIdx.x;
  if (e < N_EDGES) atomicAdd(&deg[ei[N_EDGES + e]], 1);
}

// ---------- CSR build: hierarchical exclusive scan (3 phases, all parallel) ----------
__global__ __launch_bounds__(256) void k_scan1(const int* __restrict__ deg, int* __restrict__ bsum) {
  int i = blockIdx.x * 256 + threadIdx.x;
  int v = (i < N_NODES) ? deg[i] : 0;
  for (int o = 32; o; o >>= 1) v += __shfl_xor(v, o);
  __shared__ int sh[4];
  if ((threadIdx.x & 63) == 0) sh[threadIdx.x >> 6] = v;
  __syncthreads();
  if (threadIdx.x == 0) bsum[blockIdx.x] = sh[0] + sh[1] + sh[2] + sh[3];
}

__global__ void k_scan2(int* __restrict__ bsum) {
  __shared__ int sh[512];
  int t = threadIdx.x;
  int v = (t < SCAN_NB) ? bsum[t] : 0;
  sh[t] = v; __syncthreads();
  for (int s = 1; s < 512; s <<= 1) {
    int add = (t >= s) ? sh[t - s] : 0;
    __syncthreads();
    sh[t] += add;
    __syncthreads();
  }
  if (t < SCAN_NB) bsum[t] = sh[t] - v;  // exclusive
}

__global__ __launch_bounds__(256) void k_scan3(const int* __restrict__ deg, const int* __restrict__ bsum,
                                               int* __restrict__ ofs, int* __restrict__ cursor) {
  int t = threadIdx.x;
  int i = blockIdx.x * 256 + t;
  int v = (i < N_NODES) ? deg[i] : 0;
  __shared__ int sh[256];
  sh[t] = v; __syncthreads();
  for (int s = 1; s < 256; s <<= 1) {
    int add = (t >= s) ? sh[t - s] : 0;
    __syncthreads();
    sh[t] += add;
    __syncthreads();
  }
  int excl = sh[t] - v + bsum[blockIdx.x];
  if (i < N_NODES) { ofs[i] = excl; cursor[i] = excl; }
  if (i == N_NODES - 1) ofs[N_NODES] = excl + v;
}

// ---------- CSR build: fill ----------
__global__ __launch_bounds__(256) void k_fill(const int* __restrict__ ei, int* __restrict__ cursor,
                                              int* __restrict__ csr) {
  int e = blockIdx.x * 256 + threadIdx.x;
  if (e < N_EDGES) {
    int d = ei[N_EDGES + e];
    int p = atomicAdd(&cursor[d], 1);
    csr[p] = ei[e];
  }
}

// ---------- graph offsets from sorted batch (lower_bound per graph) ----------
__global__ void k_gofs(const int* __restrict__ batch, int* __restrict__ gofs) {
  int g = threadIdx.x;  // 512
  int lo = 0, hi = N_NODES;
  while (lo < hi) { int mid = (lo + hi) >> 1; if (batch[mid] < g) lo = mid + 1; else hi = mid; }
  gofs[g] = lo;
  if (g == 0) gofs[NGRAPH] = N_NODES;
}

// ---------- gather: out[n] = h[n] + sum_{j in in(n)} h[src_j] ----------
// fp32 in/out; fp64 accumulation.
__global__ __launch_bounds__(256) void k_gather(const float* __restrict__ hf,
                                                const int* __restrict__ ofs,
                                                const int* __restrict__ csr,
                                                float* __restrict__ outQ) {
  int node = blockIdx.x * 4 + (threadIdx.x >> 6);
  int lane = threadIdx.x & 63;
  int beg = ofs[node], end = ofs[node + 1];
  float2 sv = *(const float2*)&hf[(long)node * DIM + lane * 2];
  double accx = (double)sv.x, accy = (double)sv.y;
  int j = beg;
  for (; j + 3 < end; j += 4) {
    int s0 = csr[j], s1 = csr[j + 1], s2 = csr[j + 2], s3 = csr[j + 3];
    float2 v0 = *(const float2*)&hf[(long)s0 * DIM + lane * 2];
    float2 v1 = *(const float2*)&hf[(long)s1 * DIM + lane * 2];
    float2 v2 = *(const float2*)&hf[(long)s2 * DIM + lane * 2];
    float2 v3 = *(const float2*)&hf[(long)s3 * DIM + lane * 2];
    accx += (double)v0.x; accy += (double)v0.y;
    accx += (double)v1.x; accy += (double)v1.y;
    accx += (double)v2.x; accy += (double)v2.y;
    accx += (double)v3.x; accy += (double)v3.y;
  }
  for (; j < end; j++) {
    int s0 = csr[j];
    float2 v0 = *(const float2*)&hf[(long)s0 * DIM + lane * 2];
    accx += (double)v0.x; accy += (double)v0.y;
  }
  *(float2*)&outQ[(long)node * DIM + lane * 2] = make_float2((float)accx, (float)accy);
}

// ---------- normalize codebooks (fp64) ----------
__global__ void k_cbn(const void* __restrict__ cb, double* __restrict__ cbn, const int* __restrict__ flag) {
  int isbf = flag[0];
  int b = blockIdx.x, d = threadIdx.x;  // 144 blocks x 64 threads
  double v0 = ldx(cb, (long)b * DIM + d, isbf);
  double v1 = ldx(cb, (long)b * DIM + d + 64, isbf);
  double ss = v0 * v0 + v1 * v1;
  for (int o = 32; o; o >>= 1) ss += __shfl_xor(ss, o);
  double inv = 1.0 / sqrt(ss + 1e-12);
  cbn[b * DIM + d] = v0 * inv;
  cbn[b * DIM + d + 64] = v1 * inv;
}

// ---------- Gram matrices per layer ----------
__global__ void k_gram(const double* __restrict__ cbn, double* __restrict__ G) {
  int b = blockIdx.x, t = threadIdx.x;  // 3*48*48 blocks x 64
  int l = b / (48 * 48); int rem = b % (48 * 48); int a = rem / 48, c = rem % 48;
  const double* ra = cbn + (long)(l * 48 + a) * DIM;
  const double* rc = cbn + (long)(l * 48 + c) * DIM;
  double s = ra[t] * rc[t] + ra[t + 64] * rc[t + 64];
  for (int o = 32; o; o >>= 1) s += __shfl_xor(s, o);
  if (t == 0) G[b] = s;
}

// ---------- fp32 GEMM + bias + relu: 64-row tile, 8 rows x 4 cols per thread ----------
__global__ __launch_bounds__(256) void k_gemm_relu_f(const float* __restrict__ in,
                                                     const float* __restrict__ W,
                                                     const float* __restrict__ bias,
                                                     float* __restrict__ out) {
  __shared__ float ul[64 * DIM];  // 32 KB
  int tid = threadIdx.x;
  long base = (long)blockIdx.x * 64;
  // stage 64 rows (guard tail block)
  for (int j = tid; j < 64 * DIM / 4; j += 256) {
    long row = base + (j >> 5);  // j*4/128
    float4 v = make_float4(0.f, 0.f, 0.f, 0.f);
    if (row < N_NODES) v = *(const float4*)&in[base * DIM + (long)j * 4];
    *(float4*)&ul[j * 4] = v;
  }
  __syncthreads();
  int cl = tid & 31;   // 32 col groups x 4 cols
  int rw = tid >> 5;   // 8 row groups x 8 rows
  int c0 = cl * 4;
  float acc[8][4] = {};
  for (int k = 0; k < DIM; k += 4) {
    float4 w0 = *(const float4*)&W[(k + 0) * DIM + c0];
    float4 w1 = *(const float4*)&W[(k + 1) * DIM + c0];
    float4 w2 = *(const float4*)&W[(k + 2) * DIM + c0];
    float4 w3 = *(const float4*)&W[(k + 3) * DIM + c0];
#pragma unroll
    for (int r = 0; r < 8; r++) {
      float4 u = *(const float4*)&ul[(rw * 8 + r) * DIM + k];
      acc[r][0] += u.x * w0.x + u.y * w1.x + u.z * w2.x + u.w * w3.x;
      acc[r][1] += u.x * w0.y + u.y * w1.y + u.z * w2.y + u.w * w3.y;
      acc[r][2] += u.x * w0.z + u.y * w1.z + u.z * w2.z + u.w * w3.z;
      acc[r][3] += u.x * w0.w + u.y * w1.w + u.z * w2.w + u.w * w3.w;
    }
  }
  float4 bv = *(const float4*)&bias[c0];
#pragma unroll
  for (int r = 0; r < 8; r++) {
    long row = base + rw * 8 + r;
    if (row < N_NODES) {
      float4 o;
      o.x = fmaxf(acc[r][0] + bv.x, 0.f);
      o.y = fmaxf(acc[r][1] + bv.y, 0.f);
      o.z = fmaxf(acc[r][2] + bv.z, 0.f);
      o.w = fmaxf(acc[r][3] + bv.w, 0.f);
      *(float4*)&out[row * DIM + c0] = o;
    }
  }
}

// ---------- BN stats (fp32 in, fp64 accum) ----------
__global__ __launch_bounds__(256) void k_bn_stats(const float* __restrict__ h, double* __restrict__ stats) {
  int tid = threadIdx.x; int col = tid & 127; int half = tid >> 7;
  double s = 0.0, s2 = 0.0;
  for (long r = blockIdx.x * 2 + half; r < N_NODES; r += 2048) {
    double v = (double)h[r * DIM + col];
    s += v; s2 += v * v;
  }
  __shared__ double ls[256], ls2[256];
  ls[tid] = s; ls2[tid] = s2;
  __syncthreads();
  if (tid < 128) {
    atomAddD(&stats[col], ls[tid] + ls[tid + 128]);
    atomAddD(&stats[DIM + col], ls2[tid] + ls2[tid + 128]);
  }
}

// ---------- BN prep ----------
__global__ void k_bn_prep(const double* __restrict__ stats, const void* __restrict__ gamma,
                          const void* __restrict__ beta, double* __restrict__ ss,
                          int l, const int* __restrict__ flag) {
  int isbf = flag[0];
  int d = threadIdx.x;  // 128
  double mean = stats[d] / (double)N_NODES;
  double var = stats[DIM + d] / (double)N_NODES - mean * mean;
  double sc = ldx(gamma, (long)l * DIM + d, isbf) / sqrt(var + 1e-5);
  ss[d] = sc;
  ss[DIM + d] = ldx(beta, (long)l * DIM + d, isbf) - mean * sc;
}

// ---------- normalize in place (fp32 h, fp64 math) + xs out + ||h||^2 ----------
__global__ __launch_bounds__(256) void k_normalize(float* __restrict__ h, const double* __restrict__ ss,
                                                   void* __restrict__ out, double* __restrict__ hh,
                                                   int l, const int* __restrict__ flag) {
  int isbf = flag[0];
  int tid = threadIdx.x;
  int n = blockIdx.x * 2 + (tid >> 7);
  int d = tid & 127;
  double v = (double)h[(long)n * DIM + d] * ss[d] + ss[DIM + d];
  h[(long)n * DIM + d] = (float)v;
  const long XS_BASE = (long)NGRAPH * DIM * NLAY;
  stout(out, XS_BASE + (long)n * (DIM * NLAY) + l * DIM + d, v, isbf);
  double vf = (double)(float)v;  // hh must match the stored fp32 h
  double s2 = vf * vf;
  for (int o = 32; o; o >>= 1) s2 += __shfl_xor(s2, o);
  __shared__ double wp[4];
  if ((tid & 63) == 0) wp[tid >> 6] = s2;
  __syncthreads();
  if (tid == 0) hh[n] = wp[0] + wp[1];
  else if (tid == 128) hh[n] = wp[2] + wp[3];
}

// ---------- xpool: segmented sum per graph (fp32 in, fp64 accum) ----------
__global__ __launch_bounds__(256) void k_xpool(const float* __restrict__ h, const int* __restrict__ gofs,
                                               double* __restrict__ xpool, int l) {
  int g = blockIdx.x;
  int tid = threadIdx.x;
  int d = tid & 127, half = tid >> 7;
  int beg = gofs[g], end = gofs[g + 1];
  double acc = 0.0;
  for (int n = beg + half; n < end; n += 2) acc += (double)h[(long)n * DIM + d];
  __shared__ double sh[256];
  sh[tid] = acc; __syncthreads();
  if (tid < 128) xpool[(long)g * (DIM * NLAY) + l * DIM + tid] = sh[tid] + sh[tid + 128];
}

// ---------- dotH = h @ cbn^T (48 cols), fp32 h, fp64 accum, fp32 store ----------
__global__ __launch_bounds__(256) void k_dotH(const float* __restrict__ hn,
                                              const double* __restrict__ cbnL,
                                              float* __restrict__ dH) {
  __shared__ double cl[48 * 134];
  int tid = threadIdx.x;
  for (int j = tid; j < 48 * DIM; j += 256) { int c = j >> 7, k = j & 127; cl[c * 134 + k] = cbnL[j]; }
  __syncthreads();
  int ct = tid & 7; int c0 = ct * 6; int rt = tid >> 3;
  long r0 = (long)blockIdx.x * 64 + rt; long r1 = r0 + 32;
  long r0c = r0 < N_NODES ? r0 : (N_NODES - 1);
  long r1c = r1 < N_NODES ? r1 : (N_NODES - 1);
  double acc0[6] = {}, acc1[6] = {};
  for (int k = 0; k < DIM; k += 4) {
    float4 h0 = *(const float4*)&hn[r0c * DIM + k];
    float4 h1 = *(const float4*)&hn[r1c * DIM + k];
#pragma unroll
    for (int j = 0; j < 6; j++) {
      double2 ca = *(const double2*)&cl[(c0 + j) * 134 + k];
      double2 cb = *(const double2*)&cl[(c0 + j) * 134 + k + 2];
      acc0[j] += (double)h0.x * ca.x + (double)h0.y * ca.y + (double)h0.z * cb.x + (double)h0.w * cb.y;
      acc1[j] += (double)h1.x * ca.x + (double)h1.y * ca.y + (double)h1.z * cb.x + (double)h1.w * cb.y;
    }
  }
  if (r0 < N_NODES) {
#pragma unroll
    for (int j = 0; j < 6; j++) dH[r0 * 48 + c0 + j] = (float)acc0[j];
  }
  if (r1 < N_NODES) {
#pragma unroll
    for (int j = 0; j < 6; j++) dH[r1 * 48 + c0 + j] = (float)acc1[j];
  }
}

// ---------- VQ select via dotH & Gram; ids + commit ----------
__global__ __launch_bounds__(256) void k_vq(const float* __restrict__ dH, const double* __restrict__ hh,
                                            const double* __restrict__ G, void* __restrict__ out,
                                            double* __restrict__ commit, int l, const int* __restrict__ flag) {
  int isbf = flag[0];
  __shared__ double Gl[48 * 48];
  int tid = threadIdx.x;
  for (int j = tid; j < 48 * 48; j += 256) Gl[j] = G[j];
  __syncthreads();
  long n = (long)blockIdx.x * 256 + tid;
  double csum = 0.0;
  if (n < N_NODES) {
    double dh[48];
#pragma unroll
    for (int c = 0; c < 48; c++) dh[c] = (double)dH[n * 48 + c];
    int i0 = 0; double b0 = dh[0];
#pragma unroll
    for (int c = 1; c < 16; c++) { if (dh[c] > b0) { b0 = dh[c]; i0 = c; } }
    int i1 = 0; double b1 = dh[16] - Gl[i0 * 48 + 16];
#pragma unroll
    for (int c = 1; c < 16; c++) {
      double s = dh[16 + c] - Gl[i0 * 48 + 16 + c];
      if (s > b1) { b1 = s; i1 = c; }
    }
    int i2 = 0; double b2 = dh[32] - Gl[i0 * 48 + 32] - Gl[(16 + i1) * 48 + 32];
#pragma unroll
    for (int c = 1; c < 16; c++) {
      double s = dh[32 + c] - Gl[i0 * 48 + 32 + c] - Gl[(16 + i1) * 48 + 32 + c];
      if (s > b2) { b2 = s; i2 = c; }
    }
    double r1s = hh[n] - 2.0 * b0 + Gl[i0 * 48 + i0];
    double r2s = r1s - 2.0 * b1 + Gl[(16 + i1) * 48 + 16 + i1];
    double r3s = r2s - 2.0 * b2 + Gl[(32 + i2) * 48 + 32 + i2];
    csum = r1s + r2s + r3s;
    const long IDS_BASE = (long)NGRAPH * DIM * NLAY + (long)N_NODES * DIM * NLAY + 1;
    long base = IDS_BASE + n * (NLAY * NRES) + l * NRES;
    stout(out, base + 0, (double)i0, isbf);
    stout(out, base + 1, (double)i1, isbf);
    stout(out, base + 2, (double)i2, isbf);
  }
  for (int o = 32; o; o >>= 1) csum += __shfl_xor(csum, o);
  if ((tid & 63) == 0 && csum != 0.0) atomAddD(commit, csum);
}

// ---------- final: xpool + commit -> out ----------
__global__ __launch_bounds__(256) void k_out(const double* __restrict__ xpool, const double* __restrict__ commit,
                                             void* __restrict__ out, const int* __restrict__ flag) {
  int isbf = flag[0];
  long i = (long)blockIdx.x * 256 + threadIdx.x;
  const long NP = (long)NGRAPH * DIM * NLAY;
  if (i < NP) {
    stout(out, i, xpool[i], isbf);
  } else if (i == NP) {
    double c = commit[0] * (0.25 / ((double)N_NODES * (double)DIM));
    stout(out, NP + (long)N_NODES * DIM * NLAY, c, isbf);
  }
}

extern "C" void kernel_launch(void* const* d_in, const int* in_sizes, int n_in,
                              void* d_out, int out_size, void* d_ws, size_t ws_size,
                              hipStream_t stream) {
  const void* x = d_in[0];
  const int* ei = (const int*)d_in[1];
  const int* batch = (const int*)d_in[2];
  const void* W1 = d_in[3];
  const void* b1 = d_in[4];
  const void* W2 = d_in[5];
  const void* b2 = d_in[6];
  const void* gamma = d_in[7];
  const void* beta = d_in[8];
  const void* cb = d_in[9];

  double* w = (double*)d_ws;
  double* cbn = w;                      // 18,432
  double* G = cbn + 18432;              // 6,912
  double* stats = G + 6912;             // 256
  double* ss = stats + 256;             // 256
  double* hh = ss + 256;                // 100,000
  double* xpool = hh + N_NODES;         // 196,608
  double* commit = xpool + (long)NGRAPH * DIM * NLAY;  // 1 (+pad to even)
  float* fbuf = (float*)(commit + 2);
  float* W1f = fbuf;                    // 49,152
  float* W2f = W1f + 49152;             // 49,152
  float* b1f = W2f + 49152;             // 384
  float* b2f = b1f + 384;               // 384
  float* H  = b2f + 384;                // 12,800,000 (current h, fp32)
  float* T1 = H + 12800000;             // 12,800,000
  float* T2 = T1 + 12800000;            // 12,800,000
  float* dH = T2 + 12800000;            // 4,800,000
  int* ibuf = (int*)(dH + 4800000);
  int* flag = ibuf;                     // 1 (+pad)
  int* deg = ibuf + 64;                 // N_NODES
  int* ofs = deg + N_NODES;             // N_NODES + 1
  int* cursor = ofs + N_NODES + 1;      // N_NODES
  int* csr = cursor + N_NODES;          // N_EDGES
  int* gofs = csr + N_EDGES;            // NGRAPH + 1
  int* bsum = gofs + NGRAPH + 2;        // SCAN_NB (391)

  k_detect<<<1, 256, 0, stream>>>((const unsigned int*)x, flag);
  // zero accumulators (xpool + commit contiguous)
  hipMemsetAsync(xpool, 0, ((long)NGRAPH * DIM * NLAY + 1) * sizeof(double), stream);
  hipMemsetAsync(deg, 0, N_NODES * sizeof(int), stream);
  // fp32 copies of x and weights
  k_convert_f<<<50000, 256, 0, stream>>>(x, H, (long)N_NODES * DIM, flag);
  k_convert_f<<<192, 256, 0, stream>>>(W1, W1f, 49152, flag);
  k_convert_f<<<192, 256, 0, stream>>>(W2, W2f, 49152, flag);
  k_convert_f<<<2, 256, 0, stream>>>(b1, b1f, 384, flag);
  k_convert_f<<<2, 256, 0, stream>>>(b2, b2f, 384, flag);
  k_cbn<<<NLAY * NRES * NCODE, 64, 0, stream>>>(cb, cbn, flag);
  k_gram<<<NLAY * 48 * 48, 64, 0, stream>>>(cbn, G);
  // CSR build (once; reused all 3 layers)
  k_hist<<<(N_EDGES + 255) / 256, 256, 0, stream>>>(ei, deg);
  k_scan1<<<SCAN_NB, 256, 0, stream>>>(deg, bsum);
  k_scan2<<<1, 512, 0, stream>>>(bsum);
  k_scan3<<<SCAN_NB, 256, 0, stream>>>(deg, bsum, ofs, cursor);
  k_fill<<<(N_EDGES + 255) / 256, 256, 0, stream>>>(ei, cursor, csr);
  k_gofs<<<1, NGRAPH, 0, stream>>>(batch, gofs);

  for (int l = 0; l < NLAY; l++) {
    k_gather<<<N_NODES / 4, 256, 0, stream>>>(H, ofs, csr, T1);
    k_gemm_relu_f<<<GEMM_NB, 256, 0, stream>>>(T1, W1f + l * DIM * DIM, b1f + l * DIM, T2);
    k_gemm_relu_f<<<GEMM_NB, 256, 0, stream>>>(T2, W2f + l * DIM * DIM, b2f + l * DIM, T1);
    hipMemsetAsync(stats, 0, 256 * sizeof(double), stream);
    k_bn_stats<<<1024, 256, 0, stream>>>(T1, stats);
    k_bn_prep<<<1, 128, 0, stream>>>(stats, gamma, beta, ss, l, flag);
    k_normalize<<<50000, 256, 0, stream>>>(T1, ss, d_out, hh, l, flag);
    k_xpool<<<NGRAPH, 256, 0, stream>>>(T1, gofs, xpool, l);
    k_dotH<<<1563, 256, 0, stream>>>(T1, cbn + (long)l * 48 * DIM, dH);
    k_vq<<<391, 256, 0, stream>>>(dH, hh, G + l * 48 * 48, d_out, commit, l, flag);
    // T1 becomes the new h; old H becomes scratch
    float* t = H; H = T1; T1 = T2; T2 = t;
  }
  k_out<<<769, 256, 0, stream>>>(xpool, commit, d_out, flag);
}

// Round 6
// 1699.905 us; speedup vs baseline: 1.7236x; 1.0486x over previous
//
#include <hip/hip_runtime.h>
#include <hip/hip_bf16.h>

#define N_NODES 100000
#define N_EDGES 1600000
#define DIM 128
#define NLAY 3
#define NRES 3
#define NCODE 16
#define NGRAPH 512
#define SCAN_NB ((N_NODES + 255) / 256)  // 391
#define GEMM_NB ((N_NODES + 63) / 64)    // 1563

using bf16 = __hip_bfloat16;

__device__ inline void atomAddD(double* p, double v) { unsafeAtomicAdd(p, v); }

// flag==1: external float-typed arrays are bf16; flag==0: they are fp32.
__device__ inline double ldx(const void* p, long i, int isbf) {
  if (isbf) return (double)__bfloat162float(((const bf16*)p)[i]);
  return (double)((const float*)p)[i];
}
__device__ inline void stout(void* p, long i, double v, int isbf) {
  if (isbf) ((bf16*)p)[i] = __float2bfloat16((float)v);
  else ((float*)p)[i] = (float)v;
}

// ---------- dtype detection: bf16 vs fp32 bit-pattern statistics ----------
__global__ void k_detect(const unsigned int* __restrict__ x, int* __restrict__ flag) {
  int tid = threadIdx.x;  // 256
  int cnt = 0;
  for (int j = tid; j < 1024; j += 256) {
    unsigned int u = x[j];
    int e = (u >> 7) & 0xFF;  // exponent field of the LOW u16 viewed as bf16
    cnt += (e >= 100 && e <= 135) ? 1 : 0;
  }
  __shared__ int sh[256];
  sh[tid] = cnt; __syncthreads();
  for (int s = 128; s; s >>= 1) { if (tid < s) sh[tid] += sh[tid + s]; __syncthreads(); }
  if (tid == 0) flag[0] = (sh[0] > 512) ? 1 : 0;
}

// ---------- external -> fp32 convert ----------
__global__ __launch_bounds__(256) void k_convert_f(const void* __restrict__ x, float* __restrict__ hf,
                                                   long n, const int* __restrict__ flag) {
  int isbf = flag[0];
  long i = (long)blockIdx.x * 256 + threadIdx.x;
  if (i < n) hf[i] = (float)ldx(x, i, isbf);
}

// ---------- CSR build: histogram ----------
__global__ __launch_bounds__(256) void k_hist(const int* __restrict__ ei, int* __restrict__ deg) {
  int e = blockIdx.x * 256 + threadIdx.x;
  if (e < N_EDGES) atomicAdd(&deg[ei[N_EDGES + e]], 1);
}

// ---------- CSR build: hierarchical exclusive scan (3 phases, all parallel) ----------
__global__ __launch_bounds__(256) void k_scan1(const int* __restrict__ deg, int* __restrict__ bsum) {
  int i = blockIdx.x * 256 + threadIdx.x;
  int v = (i < N_NODES) ? deg[i] : 0;
  for (int o = 32; o; o >>= 1) v += __shfl_xor(v, o);
  __shared__ int sh[4];
  if ((threadIdx.x & 63) == 0) sh[threadIdx.x >> 6] = v;
  __syncthreads();
  if (threadIdx.x == 0) bsum[blockIdx.x] = sh[0] + sh[1] + sh[2] + sh[3];
}

__global__ void k_scan2(int* __restrict__ bsum) {
  __shared__ int sh[512];
  int t = threadIdx.x;
  int v = (t < SCAN_NB) ? bsum[t] : 0;
  sh[t] = v; __syncthreads();
  for (int s = 1; s < 512; s <<= 1) {
    int add = (t >= s) ? sh[t - s] : 0;
    __syncthreads();
    sh[t] += add;
    __syncthreads();
  }
  if (t < SCAN_NB) bsum[t] = sh[t] - v;  // exclusive
}

__global__ __launch_bounds__(256) void k_scan3(const int* __restrict__ deg, const int* __restrict__ bsum,
                                               int* __restrict__ ofs, int* __restrict__ cursor) {
  int t = threadIdx.x;
  int i = blockIdx.x * 256 + t;
  int v = (i < N_NODES) ? deg[i] : 0;
  __shared__ int sh[256];
  sh[t] = v; __syncthreads();
  for (int s = 1; s < 256; s <<= 1) {
    int add = (t >= s) ? sh[t - s] : 0;
    __syncthreads();
    sh[t] += add;
    __syncthreads();
  }
  int excl = sh[t] - v + bsum[blockIdx.x];
  if (i < N_NODES) { ofs[i] = excl; cursor[i] = excl; }
  if (i == N_NODES - 1) ofs[N_NODES] = excl + v;
}

// ---------- CSR build: fill ----------
__global__ __launch_bounds__(256) void k_fill(const int* __restrict__ ei, int* __restrict__ cursor,
                                              int* __restrict__ csr) {
  int e = blockIdx.x * 256 + threadIdx.x;
  if (e < N_EDGES) {
    int d = ei[N_EDGES + e];
    int p = atomicAdd(&cursor[d], 1);
    csr[p] = ei[e];
  }
}

// ---------- gather: out[n] = h[n] + sum_{j in in(n)} h[src_j] ----------
// fp32 in/out; fp64 accumulation.
__global__ __launch_bounds__(256) void k_gather(const float* __restrict__ hf,
                                                const int* __restrict__ ofs,
                                                const int* __restrict__ csr,
                                                float* __restrict__ outQ) {
  int node = blockIdx.x * 4 + (threadIdx.x >> 6);
  int lane = threadIdx.x & 63;
  int beg = ofs[node], end = ofs[node + 1];
  float2 sv = *(const float2*)&hf[(long)node * DIM + lane * 2];
  double accx = (double)sv.x, accy = (double)sv.y;
  int j = beg;
  for (; j + 3 < end; j += 4) {
    int s0 = csr[j], s1 = csr[j + 1], s2 = csr[j + 2], s3 = csr[j + 3];
    float2 v0 = *(const float2*)&hf[(long)s0 * DIM + lane * 2];
    float2 v1 = *(const float2*)&hf[(long)s1 * DIM + lane * 2];
    float2 v2 = *(const float2*)&hf[(long)s2 * DIM + lane * 2];
    float2 v3 = *(const float2*)&hf[(long)s3 * DIM + lane * 2];
    accx += (double)v0.x; accy += (double)v0.y;
    accx += (double)v1.x; accy += (double)v1.y;
    accx += (double)v2.x; accy += (double)v2.y;
    accx += (double)v3.x; accy += (double)v3.y;
  }
  for (; j < end; j++) {
    int s0 = csr[j];
    float2 v0 = *(const float2*)&hf[(long)s0 * DIM + lane * 2];
    accx += (double)v0.x; accy += (double)v0.y;
  }
  *(float2*)&outQ[(long)node * DIM + lane * 2] = make_float2((float)accx, (float)accy);
}

// ---------- normalize codebooks (fp64) ----------
__global__ void k_cbn(const void* __restrict__ cb, double* __restrict__ cbn, const int* __restrict__ flag) {
  int isbf = flag[0];
  int b = blockIdx.x, d = threadIdx.x;  // 144 blocks x 64 threads
  double v0 = ldx(cb, (long)b * DIM + d, isbf);
  double v1 = ldx(cb, (long)b * DIM + d + 64, isbf);
  double ss = v0 * v0 + v1 * v1;
  for (int o = 32; o; o >>= 1) ss += __shfl_xor(ss, o);
  double inv = 1.0 / sqrt(ss + 1e-12);
  cbn[b * DIM + d] = v0 * inv;
  cbn[b * DIM + d + 64] = v1 * inv;
}

// ---------- Gram matrices per layer ----------
__global__ void k_gram(const double* __restrict__ cbn, double* __restrict__ G) {
  int b = blockIdx.x, t = threadIdx.x;  // 3*48*48 blocks x 64
  int l = b / (48 * 48); int rem = b % (48 * 48); int a = rem / 48, c = rem % 48;
  const double* ra = cbn + (long)(l * 48 + a) * DIM;
  const double* rc = cbn + (long)(l * 48 + c) * DIM;
  double s = ra[t] * rc[t] + ra[t + 64] * rc[t + 64];
  for (int o = 32; o; o >>= 1) s += __shfl_xor(s, o);
  if (t == 0) G[b] = s;
}

// ---------- fp32 GEMM + bias + relu: 64-row tile, 8 rows x 4 cols per thread ----------
// (VERBATIM Round-3 kernel — h numerics proven against the harness reference)
__global__ __launch_bounds__(256) void k_gemm_relu_f(const float* __restrict__ in,
                                                     const float* __restrict__ W,
                                                     const float* __restrict__ bias,
                                                     float* __restrict__ out) {
  __shared__ float ul[64 * DIM];  // 32 KB
  int tid = threadIdx.x;
  long base = (long)blockIdx.x * 64;
  // stage 64 rows (guard tail block)
  for (int j = tid; j < 64 * DIM / 4; j += 256) {
    long row = base + (j >> 5);  // j*4/128
    float4 v = make_float4(0.f, 0.f, 0.f, 0.f);
    if (row < N_NODES) v = *(const float4*)&in[base * DIM + (long)j * 4];
    *(float4*)&ul[j * 4] = v;
  }
  __syncthreads();
  int cl = tid & 31;   // 32 col groups x 4 cols
  int rw = tid >> 5;   // 8 row groups x 8 rows
  int c0 = cl * 4;
  float acc[8][4] = {};
  for (int k = 0; k < DIM; k += 4) {
    float4 w0 = *(const float4*)&W[(k + 0) * DIM + c0];
    float4 w1 = *(const float4*)&W[(k + 1) * DIM + c0];
    float4 w2 = *(const float4*)&W[(k + 2) * DIM + c0];
    float4 w3 = *(const float4*)&W[(k + 3) * DIM + c0];
#pragma unroll
    for (int r = 0; r < 8; r++) {
      float4 u = *(const float4*)&ul[(rw * 8 + r) * DIM + k];
      acc[r][0] += u.x * w0.x + u.y * w1.x + u.z * w2.x + u.w * w3.x;
      acc[r][1] += u.x * w0.y + u.y * w1.y + u.z * w2.y + u.w * w3.y;
      acc[r][2] += u.x * w0.z + u.y * w1.z + u.z * w2.z + u.w * w3.z;
      acc[r][3] += u.x * w0.w + u.y * w1.w + u.z * w2.w + u.w * w3.w;
    }
  }
  float4 bv = *(const float4*)&bias[c0];
#pragma unroll
  for (int r = 0; r < 8; r++) {
    long row = base + rw * 8 + r;
    if (row < N_NODES) {
      float4 o;
      o.x = fmaxf(acc[r][0] + bv.x, 0.f);
      o.y = fmaxf(acc[r][1] + bv.y, 0.f);
      o.z = fmaxf(acc[r][2] + bv.z, 0.f);
      o.w = fmaxf(acc[r][3] + bv.w, 0.f);
      *(float4*)&out[row * DIM + c0] = o;
    }
  }
}

// ---------- BN stats (fp32 in, fp64 accum) — VERBATIM Round-3 kernel ----------
__global__ __launch_bounds__(256) void k_bn_stats(const float* __restrict__ h, double* __restrict__ stats) {
  int tid = threadIdx.x; int col = tid & 127; int half = tid >> 7;
  double s = 0.0, s2 = 0.0;
  for (long r = blockIdx.x * 2 + half; r < N_NODES; r += 2048) {
    double v = (double)h[r * DIM + col];
    s += v; s2 += v * v;
  }
  __shared__ double ls[256], ls2[256];
  ls[tid] = s; ls2[tid] = s2;
  __syncthreads();
  if (tid < 128) {
    atomAddD(&stats[col], ls[tid] + ls[tid + 128]);
    atomAddD(&stats[DIM + col], ls2[tid] + ls2[tid + 128]);
  }
}

// ---------- BN prep ----------
__global__ void k_bn_prep(const double* __restrict__ stats, const void* __restrict__ gamma,
                          const void* __restrict__ beta, double* __restrict__ ss,
                          int l, const int* __restrict__ flag) {
  int isbf = flag[0];
  int d = threadIdx.x;  // 128
  double mean = stats[d] / (double)N_NODES;
  double var = stats[DIM + d] / (double)N_NODES - mean * mean;
  double sc = ldx(gamma, (long)l * DIM + d, isbf) / sqrt(var + 1e-5);
  ss[d] = sc;
  ss[DIM + d] = ldx(beta, (long)l * DIM + d, isbf) - mean * sc;
}

// ---------- slim fused post: normalize + xs + hh + xpool, per 64-row tile ----------
// Per-element normalize arithmetic identical to R3's k_normalize (proven in R4/R5:
// outputs 0/1/2 all passed through this kernel).
__global__ __launch_bounds__(256) void k_post(float* __restrict__ h,
                                              const double* __restrict__ ss,
                                              const int* __restrict__ batch,
                                              void* __restrict__ out,
                                              double* __restrict__ xpool,
                                              double* __restrict__ hh,
                                              int l, const int* __restrict__ flag) {
  __shared__ float hl[64 * 132];   // normalized tile (fp32), padded
  __shared__ double hq[64 * 4];    // ||h||^2 quarter-partials
  __shared__ int sbat[64];
  int isbf = flag[0];
  int tid = threadIdx.x;
  long base = (long)blockIdx.x * 64;
  if (tid < 64) {
    long row = base + tid;
    sbat[tid] = (row < N_NODES) ? batch[row] : -1;
  }
  // phase 1: normalize (fp64 math) + write h + xs + stage tile
  int d = tid & 127, half = tid >> 7;
  double sc = ss[d], sh = ss[DIM + d];
  const long XS_BASE = (long)NGRAPH * DIM * NLAY;
  for (int rr = half; rr < 64; rr += 2) {
    long row = base + rr;
    float vf = 0.f;
    if (row < N_NODES) {
      double v = (double)h[row * DIM + d] * sc + sh;
      vf = (float)v;
      h[row * DIM + d] = vf;
      stout(out, XS_BASE + row * (DIM * NLAY) + l * DIM + d, v, isbf);
    }
    hl[rr * 132 + d] = vf;
  }
  __syncthreads();
  // phase 2: hh quarter-partials
  {
    int row = tid >> 2, q = tid & 3;
    double s2 = 0.0;
    const float* hp = &hl[row * 132 + q * 32];
#pragma unroll
    for (int i = 0; i < 32; i++) { double v = (double)hp[i]; s2 += v * v; }
    hq[row * 4 + q] = s2;
  }
  __syncthreads();
  // phase 3 (wave 0): hh write ; (waves 2-3): xpool segments
  if (tid < 64) {
    long n = base + tid;
    if (n < N_NODES) hh[n] = hq[tid * 4] + hq[tid * 4 + 1] + hq[tid * 4 + 2] + hq[tid * 4 + 3];
  } else if (tid >= 128) {
    int dd = tid - 128;
    int g = sbat[0];
    double acc = 0.0;
    for (int r = 0; r < 64; r++) {
      int gg = sbat[r];
      if (gg < 0) break;
      if (gg != g) {
        atomAddD(&xpool[(long)g * (DIM * NLAY) + l * DIM + dd], acc);
        acc = 0.0; g = gg;
      }
      acc += (double)hl[r * 132 + dd];
    }
    atomAddD(&xpool[(long)g * (DIM * NLAY) + l * DIM + dd], acc);
  }
}

// ---------- dotH = h @ cbn^T (48 cols), fp32 h, fp64 cbn LDS, fp64 accum, fp32 store ----------
// (verbatim Round-3 kernel — ID-path numerics proven against the harness reference)
__global__ __launch_bounds__(256) void k_dotH(const float* __restrict__ hn,
                                              const double* __restrict__ cbnL,
                                              float* __restrict__ dH) {
  __shared__ double cl[48 * 134];
  int tid = threadIdx.x;
  for (int j = tid; j < 48 * DIM; j += 256) { int c = j >> 7, k = j & 127; cl[c * 134 + k] = cbnL[j]; }
  __syncthreads();
  int ct = tid & 7; int c0 = ct * 6; int rt = tid >> 3;
  long r0 = (long)blockIdx.x * 64 + rt; long r1 = r0 + 32;
  long r0c = r0 < N_NODES ? r0 : (N_NODES - 1);
  long r1c = r1 < N_NODES ? r1 : (N_NODES - 1);
  double acc0[6] = {}, acc1[6] = {};
  for (int k = 0; k < DIM; k += 4) {
    float4 h0 = *(const float4*)&hn[r0c * DIM + k];
    float4 h1 = *(const float4*)&hn[r1c * DIM + k];
#pragma unroll
    for (int j = 0; j < 6; j++) {
      double2 ca = *(const double2*)&cl[(c0 + j) * 134 + k];
      double2 cb = *(const double2*)&cl[(c0 + j) * 134 + k + 2];
      acc0[j] += (double)h0.x * ca.x + (double)h0.y * ca.y + (double)h0.z * cb.x + (double)h0.w * cb.y;
      acc1[j] += (double)h1.x * ca.x + (double)h1.y * ca.y + (double)h1.z * cb.x + (double)h1.w * cb.y;
    }
  }
  if (r0 < N_NODES) {
#pragma unroll
    for (int j = 0; j < 6; j++) dH[r0 * 48 + c0 + j] = (float)acc0[j];
  }
  if (r1 < N_NODES) {
#pragma unroll
    for (int j = 0; j < 6; j++) dH[r1 * 48 + c0 + j] = (float)acc1[j];
  }
}

// ---------- VQ select via dotH & Gram; ids + commit (verbatim Round-3 kernel) ----------
__global__ __launch_bounds__(256) void k_vq(const float* __restrict__ dH, const double* __restrict__ hh,
                                            const double* __restrict__ G, void* __restrict__ out,
                                            double* __restrict__ commit, int l, const int* __restrict__ flag) {
  int isbf = flag[0];
  __shared__ double Gl[48 * 48];
  int tid = threadIdx.x;
  for (int j = tid; j < 48 * 48; j += 256) Gl[j] = G[j];
  __syncthreads();
  long n = (long)blockIdx.x * 256 + tid;
  double csum = 0.0;
  if (n < N_NODES) {
    double dh[48];
#pragma unroll
    for (int c = 0; c < 48; c++) dh[c] = (double)dH[n * 48 + c];
    int i0 = 0; double b0 = dh[0];
#pragma unroll
    for (int c = 1; c < 16; c++) { if (dh[c] > b0) { b0 = dh[c]; i0 = c; } }
    int i1 = 0; double b1 = dh[16] - Gl[i0 * 48 + 16];
#pragma unroll
    for (int c = 1; c < 16; c++) {
      double s = dh[16 + c] - Gl[i0 * 48 + 16 + c];
      if (s > b1) { b1 = s; i1 = c; }
    }
    int i2 = 0; double b2 = dh[32] - Gl[i0 * 48 + 32] - Gl[(16 + i1) * 48 + 32];
#pragma unroll
    for (int c = 1; c < 16; c++) {
      double s = dh[32 + c] - Gl[i0 * 48 + 32 + c] - Gl[(16 + i1) * 48 + 32 + c];
      if (s > b2) { b2 = s; i2 = c; }
    }
    double r1s = hh[n] - 2.0 * b0 + Gl[i0 * 48 + i0];
    double r2s = r1s - 2.0 * b1 + Gl[(16 + i1) * 48 + 16 + i1];
    double r3s = r2s - 2.0 * b2 + Gl[(32 + i2) * 48 + 32 + i2];
    csum = r1s + r2s + r3s;
    const long IDS_BASE = (long)NGRAPH * DIM * NLAY + (long)N_NODES * DIM * NLAY + 1;
    long base = IDS_BASE + n * (NLAY * NRES) + l * NRES;
    stout(out, base + 0, (double)i0, isbf);
    stout(out, base + 1, (double)i1, isbf);
    stout(out, base + 2, (double)i2, isbf);
  }
  for (int o = 32; o; o >>= 1) csum += __shfl_xor(csum, o);
  if ((tid & 63) == 0 && csum != 0.0) atomAddD(commit, csum);
}

// ---------- final: xpool + commit -> out ----------
__global__ __launch_bounds__(256) void k_out(const double* __restrict__ xpool, const double* __restrict__ commit,
                                             void* __restrict__ out, const int* __restrict__ flag) {
  int isbf = flag[0];
  long i = (long)blockIdx.x * 256 + threadIdx.x;
  const long NP = (long)NGRAPH * DIM * NLAY;
  if (i < NP) {
    stout(out, i, xpool[i], isbf);
  } else if (i == NP) {
    double c = commit[0] * (0.25 / ((double)N_NODES * (double)DIM));
    stout(out, NP + (long)N_NODES * DIM * NLAY, c, isbf);
  }
}

extern "C" void kernel_launch(void* const* d_in, const int* in_sizes, int n_in,
                              void* d_out, int out_size, void* d_ws, size_t ws_size,
                              hipStream_t stream) {
  const void* x = d_in[0];
  const int* ei = (const int*)d_in[1];
  const int* batch = (const int*)d_in[2];
  const void* W1 = d_in[3];
  const void* b1 = d_in[4];
  const void* W2 = d_in[5];
  const void* b2 = d_in[6];
  const void* gamma = d_in[7];
  const void* beta = d_in[8];
  const void* cb = d_in[9];

  double* w = (double*)d_ws;
  double* cbn = w;                      // 18,432
  double* G = cbn + 18432;              // 6,912
  double* stats = G + 6912;             // 256
  double* ss = stats + 256;             // 256
  double* hh = ss + 256;                // 100,000
  double* xpool = hh + N_NODES;         // 196,608
  double* commit = xpool + (long)NGRAPH * DIM * NLAY;  // 1 (+1 pad)
  float* W1f = (float*)(commit + 2);    // 49,152
  float* W2f = W1f + 49152;             // 49,152
  float* b1f = W2f + 49152;             // 384
  float* b2f = b1f + 384;               // 384
  float* H  = b2f + 384;                // 12,800,000 (current h, fp32)
  float* T1 = H + 12800000;             // 12,800,000
  float* T2 = T1 + 12800000;            // 12,800,000
  float* dH = T2 + 12800000;            // 4,800,000
  int* ibuf = (int*)(dH + 4800000);
  int* flag = ibuf;                     // 1 (+pad)
  int* deg = ibuf + 64;                 // N_NODES
  int* ofs = deg + N_NODES;             // N_NODES + 1
  int* cursor = ofs + N_NODES + 1;      // N_NODES
  int* csr = cursor + N_NODES;          // N_EDGES
  int* bsum = csr + N_EDGES;            // SCAN_NB (391)

  k_detect<<<1, 256, 0, stream>>>((const unsigned int*)x, flag);
  // zero accumulators (xpool + commit contiguous)
  hipMemsetAsync(xpool, 0, ((long)NGRAPH * DIM * NLAY + 1) * sizeof(double), stream);
  hipMemsetAsync(deg, 0, N_NODES * sizeof(int), stream);
  // fp32 copies of x and weights
  k_convert_f<<<50000, 256, 0, stream>>>(x, H, (long)N_NODES * DIM, flag);
  k_convert_f<<<192, 256, 0, stream>>>(W1, W1f, 49152, flag);
  k_convert_f<<<192, 256, 0, stream>>>(W2, W2f, 49152, flag);
  k_convert_f<<<2, 256, 0, stream>>>(b1, b1f, 384, flag);
  k_convert_f<<<2, 256, 0, stream>>>(b2, b2f, 384, flag);
  k_cbn<<<NLAY * NRES * NCODE, 64, 0, stream>>>(cb, cbn, flag);
  k_gram<<<NLAY * 48 * 48, 64, 0, stream>>>(cbn, G);
  // CSR build (once; reused all 3 layers)
  k_hist<<<(N_EDGES + 255) / 256, 256, 0, stream>>>(ei, deg);
  k_scan1<<<SCAN_NB, 256, 0, stream>>>(deg, bsum);
  k_scan2<<<1, 512, 0, stream>>>(bsum);
  k_scan3<<<SCAN_NB, 256, 0, stream>>>(deg, bsum, ofs, cursor);
  k_fill<<<(N_EDGES + 255) / 256, 256, 0, stream>>>(ei, cursor, csr);

  for (int l = 0; l < NLAY; l++) {
    k_gather<<<N_NODES / 4, 256, 0, stream>>>(H, ofs, csr, T1);
    k_gemm_relu_f<<<GEMM_NB, 256, 0, stream>>>(T1, W1f + l * DIM * DIM, b1f + l * DIM, T2);
    k_gemm_relu_f<<<GEMM_NB, 256, 0, stream>>>(T2, W2f + l * DIM * DIM, b2f + l * DIM, T1);
    hipMemsetAsync(stats, 0, 256 * sizeof(double), stream);
    k_bn_stats<<<1024, 256, 0, stream>>>(T1, stats);
    k_bn_prep<<<1, 128, 0, stream>>>(stats, gamma, beta, ss, l, flag);
    k_post<<<GEMM_NB, 256, 0, stream>>>(T1, ss, batch, d_out, xpool, hh, l, flag);
    k_dotH<<<1563, 256, 0, stream>>>(T1, cbn + (long)l * 48 * DIM, dH);
    k_vq<<<391, 256, 0, stream>>>(dH, hh, G + l * 48 * 48, d_out, commit, l, flag);
    // T1 becomes the new h; old H becomes scratch
    float* t = H; H = T1; T1 = T2; T2 = t;
  }
  k_out<<<769, 256, 0, stream>>>(xpool, commit, d_out, flag);
}